// Round 1
// baseline (1053.984 us; speedup 1.0000x reference)
//
#include <hip/hip_runtime.h>
#include <math.h>

// Problem constants (match reference file)
#define NN   8192   // nodes
#define DF   64     // feature dim
#define KK   16     // k samples
#define MAXNBR 34   // self + up to 32 neighbors (+1 slack)
#define MAXC (MAXNBR * KK)  // 544 max candidate values

__global__ __launch_bounds__(256)
void attn_sample_kernel(const float* __restrict__ x,
                        const float* __restrict__ adj,
                        const int*   __restrict__ cs,
                        int*         __restrict__ out)
{
    const int i = blockIdx.x;
    const int t = threadIdx.x;

    __shared__ float xi[DF];
    __shared__ unsigned mask[NN / 32];       // 1 KB bitmask over node ids
    __shared__ int nbrs[MAXNBR];
    __shared__ int nnbr;
    __shared__ int uniq[MAXC];
    __shared__ float sims[MAXC];
    __shared__ int nuniq;
    __shared__ unsigned long long best;

    if (t < DF) xi[t] = x[(size_t)i * DF + t];
    for (int w = t; w < NN / 32; w += 256) mask[w] = 0u;
    if (t == 0) { nbrs[0] = i; nnbr = 1; nuniq = 0; }
    __syncthreads();

    // ---- scan adjacency row i for ones (<= 32 by construction) ----
    const float4* row4 = reinterpret_cast<const float4*>(adj + (size_t)i * NN);
    for (int j = t; j < NN / 4; j += 256) {
        float4 v = row4[j];
        int base = 4 * j;
        if (v.x > 0.f) { int s = atomicAdd(&nnbr, 1); if (s < MAXNBR) nbrs[s] = base; }
        if (v.y > 0.f) { int s = atomicAdd(&nnbr, 1); if (s < MAXNBR) nbrs[s] = base + 1; }
        if (v.z > 0.f) { int s = atomicAdd(&nnbr, 1); if (s < MAXNBR) nbrs[s] = base + 2; }
        if (v.w > 0.f) { int s = atomicAdd(&nnbr, 1); if (s < MAXNBR) nbrs[s] = base + 3; }
    }
    __syncthreads();

    // ---- gather candidate samples, dedup via bitmask ----
    int M = nnbr; if (M > MAXNBR) M = MAXNBR;
    int total = M * KK;
    for (int q = t; q < total; q += 256) {
        int node = nbrs[q >> 4];
        int v = cs[(size_t)node * KK + (q & 15)];
        unsigned bit = 1u << (v & 31);
        unsigned old = atomicOr(&mask[v >> 5], bit);
        if (!(old & bit)) {
            int s = atomicAdd(&nuniq, 1);
            uniq[s] = v;
        }
    }
    __syncthreads();

    const int nu = nuniq;

    // ---- sims: strict sequential FMA chain over d (bit-match CPU BLAS k-loop) ----
    for (int u = t; u < nu; u += 256) {
        const float4* xc4 = reinterpret_cast<const float4*>(x + (size_t)uniq[u] * DF);
        float acc = 0.f;
        #pragma unroll
        for (int d4 = 0; d4 < DF / 4; ++d4) {
            float4 v = xc4[d4];
            acc = fmaf(xi[4 * d4 + 0], v.x, acc);
            acc = fmaf(xi[4 * d4 + 1], v.y, acc);
            acc = fmaf(xi[4 * d4 + 2], v.z, acc);
            acc = fmaf(xi[4 * d4 + 3], v.w, acc);
        }
        sims[u] = acc;
    }
    __syncthreads();

    if (nu >= KK) {
        // ---- iterative block-wide argmax: max sim, tie -> smaller candidate value ----
        for (int j = 0; j < KK; ++j) {
            if (t == 0) best = 0ULL;
            __syncthreads();
            unsigned long long loc = 0ULL;
            for (int u = t; u < nu; u += 256) {
                unsigned fb = __float_as_uint(sims[u]);
                fb = (fb & 0x80000000u) ? ~fb : (fb | 0x80000000u);  // order-preserving map
                unsigned long long key =
                    ((unsigned long long)fb << 23) |
                    ((unsigned long long)(unsigned)(8191 - uniq[u]) << 10) |
                    (unsigned long long)(unsigned)u;
                if (key > loc) loc = key;
            }
            atomicMax(&best, loc);
            __syncthreads();
            if (t == 0) {
                int u = (int)(best & 1023ULL);
                out[(size_t)i * KK + j] = uniq[u];
                sims[u] = -INFINITY;   // remove winner
            }
            __syncthreads();
        }
    } else {
        // ---- rare branch: fewer than K uniques -> sorted uniques + pad with own samples ----
        if (t == 0) {
            int cnt = 0;
            int srt[KK];
            for (int w = 0; w < NN / 32 && cnt < KK; ++w) {
                unsigned m = mask[w];
                while (m && cnt < KK) {
                    int b = __ffs(m) - 1;
                    m &= m - 1;
                    srt[cnt++] = w * 32 + b;
                }
            }
            for (int j = 0; j < KK; ++j) {
                int v;
                if (j < nu) {
                    v = srt[j];
                } else {
                    int idx = j - nu;
                    idx = idx < 0 ? 0 : (idx > KK - 1 ? KK - 1 : idx);
                    v = cs[(size_t)i * KK + idx];
                }
                out[(size_t)i * KK + j] = v;
            }
        }
    }
}

extern "C" void kernel_launch(void* const* d_in, const int* in_sizes, int n_in,
                              void* d_out, int out_size, void* d_ws, size_t ws_size,
                              hipStream_t stream)
{
    const float* x   = (const float*)d_in[0];
    const float* adj = (const float*)d_in[1];
    const int*   cs  = (const int*)d_in[2];
    int* out = (int*)d_out;

    attn_sample_kernel<<<NN, 256, 0, stream>>>(x, adj, cs, out);
}

// Round 2
// 185.742 us; speedup vs baseline: 5.6744x; 5.6744x over previous
//
#include <hip/hip_runtime.h>
#include <math.h>

// Problem constants (match reference file)
#define NN   8192   // nodes
#define DF   64     // feature dim
#define KK   16     // k samples
#define MAXNBR 34   // self + up to 32 neighbors (+1 slack)
#define SLOTS 9     // ceil(34*16 / 64) candidate slots per lane
#define WPB  4      // waves per block

__global__ __launch_bounds__(256)
void attn_wave_kernel(const float* __restrict__ x,
                      const float* __restrict__ adj,
                      const int*   __restrict__ cs,
                      int*         __restrict__ out)
{
    const int w    = threadIdx.x >> 6;          // wave id within block
    const int lane = threadIdx.x & 63;
    const int i    = blockIdx.x * WPB + w;      // node id (one wave per node)

    __shared__ unsigned mask[WPB][NN / 32];     // 1 KB bitmask per wave
    __shared__ float    xi[WPB][DF];
    __shared__ int      nbrs[WPB][MAXNBR + 2];
    __shared__ int      nnbr[WPB];

    // ---- phase A: init ----
    xi[w][lane] = x[(size_t)i * DF + lane];     // DF == 64 == wave size
    for (int m = lane; m < NN / 32; m += 64) mask[w][m] = 0u;
    if (lane == 0) { nbrs[w][0] = i; nnbr[w] = 1; }
    __syncthreads();

    // ---- phase B: scan adjacency row i (the 256 MB HBM stream) ----
    const float4* row4 = reinterpret_cast<const float4*>(adj + (size_t)i * NN);
    #pragma unroll 4
    for (int r = 0; r < NN / 4 / 64; ++r) {
        float4 v = row4[lane + 64 * r];
        int base = 4 * (lane + 64 * r);
        if (v.x > 0.f) { int s = atomicAdd(&nnbr[w], 1); if (s < MAXNBR) nbrs[w][s] = base; }
        if (v.y > 0.f) { int s = atomicAdd(&nnbr[w], 1); if (s < MAXNBR) nbrs[w][s] = base + 1; }
        if (v.z > 0.f) { int s = atomicAdd(&nnbr[w], 1); if (s < MAXNBR) nbrs[w][s] = base + 2; }
        if (v.w > 0.f) { int s = atomicAdd(&nnbr[w], 1); if (s < MAXNBR) nbrs[w][s] = base + 3; }
    }
    __syncthreads();

    // ---- phase C: gather candidate samples, dedup into per-lane register slots ----
    int M = nnbr[w]; if (M > MAXNBR) M = MAXNBR;
    const int total = M * KK;                    // <= 544
    int  vals[SLOTS];
    bool valid[SLOTS];
    #pragma unroll
    for (int r = 0; r < SLOTS; ++r) {
        valid[r] = false;
        vals[r]  = 0;
        int q = lane + 64 * r;
        if (q < total) {
            int node = nbrs[w][q >> 4];
            int v = cs[(size_t)node * KK + (q & 15)];
            unsigned bit = 1u << (v & 31);
            unsigned old = atomicOr(&mask[w][v >> 5], bit);
            if (!(old & bit)) { valid[r] = true; vals[r] = v; }
        }
    }

    // unique count (wave-wide sum)
    int myc = 0;
    #pragma unroll
    for (int r = 0; r < SLOTS; ++r) myc += valid[r] ? 1 : 0;
    int nu = myc;
    #pragma unroll
    for (int off = 32; off; off >>= 1) nu += __shfl_xor(nu, off);

    // ---- phase D: sims (strict sequential FMA chain, bit-matches round-1) ----
    unsigned long long keys[SLOTS];
    #pragma unroll
    for (int r = 0; r < SLOTS; ++r) {
        unsigned long long key = 0ULL;
        if (valid[r]) {
            const float4* xc4 = reinterpret_cast<const float4*>(x + (size_t)vals[r] * DF);
            float acc = 0.f;
            #pragma unroll
            for (int d4 = 0; d4 < DF / 4; ++d4) {
                float4 v = xc4[d4];
                acc = fmaf(xi[w][4 * d4 + 0], v.x, acc);
                acc = fmaf(xi[w][4 * d4 + 1], v.y, acc);
                acc = fmaf(xi[w][4 * d4 + 2], v.z, acc);
                acc = fmaf(xi[w][4 * d4 + 3], v.w, acc);
            }
            unsigned fb = __float_as_uint(acc);
            fb = (fb & 0x80000000u) ? ~fb : (fb | 0x80000000u);   // order-preserving
            key = ((unsigned long long)fb << 17) |
                  ((unsigned long long)(unsigned)(8191 - vals[r]) << 4) |
                  (unsigned long long)(unsigned)r;
        }
        keys[r] = key;
    }
    __syncthreads();   // mask atomics complete before rare-branch mask read

    // ---- phase E: selection ----
    if (nu >= KK) {
        int myout = 0;
        for (int j = 0; j < KK; ++j) {
            unsigned long long m = 0ULL;
            #pragma unroll
            for (int r = 0; r < SLOTS; ++r) m = keys[r] > m ? keys[r] : m;
            #pragma unroll
            for (int off = 32; off; off >>= 1) {
                unsigned long long o = __shfl_xor(m, off);
                m = o > m ? o : m;
            }
            int v = 8191 - (int)((m >> 4) & 0x1FFFULL);
            if (lane == j) myout = v;
            int rr = (int)(m & 15ULL);
            #pragma unroll
            for (int r = 0; r < SLOTS; ++r)
                if (r == rr && keys[r] == m) keys[r] = 0ULL;
        }
        if (lane < KK) out[(size_t)i * KK + lane] = myout;
    } else {
        // rare: fewer than K uniques -> sorted uniques + pad with own samples
        if (lane == 0) {
            int cnt = 0;
            for (int mw = 0; mw < NN / 32 && cnt < KK; ++mw) {
                unsigned b = mask[w][mw];
                while (b && cnt < KK) {
                    int bit = __ffs(b) - 1;
                    b &= b - 1;
                    nbrs[w][cnt++] = mw * 32 + bit;   // reuse LDS as sorted-unique buf
                }
            }
            for (int j = 0; j < KK; ++j) {
                int v;
                if (j < nu) {
                    v = nbrs[w][j];
                } else {
                    int idx = j - nu;
                    if (idx > KK - 1) idx = KK - 1;
                    v = cs[(size_t)i * KK + idx];
                }
                out[(size_t)i * KK + j] = v;
            }
        }
    }
}

extern "C" void kernel_launch(void* const* d_in, const int* in_sizes, int n_in,
                              void* d_out, int out_size, void* d_ws, size_t ws_size,
                              hipStream_t stream)
{
    const float* x   = (const float*)d_in[0];
    const float* adj = (const float*)d_in[1];
    const int*   cs  = (const int*)d_in[2];
    int* out = (int*)d_out;

    attn_wave_kernel<<<NN / WPB, 256, 0, stream>>>(x, adj, cs, out);
}